// Round 4
// baseline (436.130 us; speedup 1.0000x reference)
//
#include <hip/hip_runtime.h>
#include <hip/hip_bf16.h>

typedef short bf16x8 __attribute__((ext_vector_type(8)));
typedef short bf16x4 __attribute__((ext_vector_type(4)));
typedef float f32x4 __attribute__((ext_vector_type(4)));

#define B_ 32
#define T_ 2048
#define C_ 1024
#define H_ 64

// 16x16x16 bf16 MFMA. NOTE: __has_builtin does not report amdgcn builtins in
// the HOST pass of HIP compilation (aux-target quirk) -- R3 failed exactly
// there. Gate on __HIP_DEVICE_COMPILE__: device pass dispatches by
// __has_builtin; host pass parses a dummy (never codegens device bodies).
#if defined(__HIP_DEVICE_COMPILE__)
#if __has_builtin(__builtin_amdgcn_mfma_f32_16x16x16bf16_1k)
#define MFMA16(A, Bo, Co) __builtin_amdgcn_mfma_f32_16x16x16bf16_1k(A, Bo, Co, 0, 0, 0)
#elif __has_builtin(__builtin_amdgcn_mfma_f32_16x16x16_bf16)
#define MFMA16(A, Bo, Co) __builtin_amdgcn_mfma_f32_16x16x16_bf16(A, Bo, Co, 0, 0, 0)
#else
static __device__ __forceinline__ f32x4 mfma16_asm(bf16x4 a, bf16x4 b, f32x4 c) {
  f32x4 d;
  asm("v_mfma_f32_16x16x16_bf16 %0, %1, %2, %3" : "=v"(d) : "v"(a), "v"(b), "v"(c));
  return d;
}
#define MFMA16(A, Bo, Co) mfma16_asm(A, Bo, Co)
#endif
#else
#define MFMA16(A, Bo, Co) (Co)  // host pass: parse-only
#endif

__device__ __forceinline__ ushort f2bf(float f) {
  union { float f; unsigned u; } v; v.f = f;
  unsigned u = v.u;
  return (ushort)((u + 0x7FFFu + ((u >> 16) & 1u)) >> 16);
}

// packed bf16 pair: lo16 = bf16(lo), hi16 = bf16(hi), RNE
__device__ __forceinline__ unsigned cvt_pk_bf16(float lo, float hi) {
  unsigned r;
  asm("v_cvt_pk_bf16_f32 %0, %1, %2" : "=v"(r) : "v"(lo), "v"(hi));
  return r;
}

__device__ __forceinline__ bf16x8 pack8(float4 a, float4 b) {
  union { __hip_bfloat162 h; short2 s; } t;
  bf16x8 r;
  t.h = __float22bfloat162_rn(make_float2(a.x, a.y)); r[0] = t.s.x; r[1] = t.s.y;
  t.h = __float22bfloat162_rn(make_float2(a.z, a.w)); r[2] = t.s.x; r[3] = t.s.y;
  t.h = __float22bfloat162_rn(make_float2(b.x, b.y)); r[4] = t.s.x; r[5] = t.s.y;
  t.h = __float22bfloat162_rn(make_float2(b.z, b.w)); r[6] = t.s.x; r[7] = t.s.y;
  return r;
}

__device__ __forceinline__ void async_copy16(void* lds, const void* g) {
  __builtin_amdgcn_global_load_lds(
      (const __attribute__((address_space(1))) unsigned int*)g,
      (__attribute__((address_space(3))) unsigned int*)lds, 16, 0, 0);
}

// Wt[n][c], n = mat*64 + h, mat: 0=Wk, 1=Wq (scaled by 1/8*log2e), 2=Wv
__global__ __launch_bounds__(256) void wconv_kernel(
    const float* __restrict__ Wk, const float* __restrict__ Wq,
    const float* __restrict__ Wv, ushort* __restrict__ Wt) {
  int idx = blockIdx.x * 256 + threadIdx.x;
  if (idx >= 3 * 64 * C_) return;
  int n = idx >> 10, c = idx & 1023;
  int mat = n >> 6, h = n & 63;
  const float* W = (mat == 0) ? Wk : (mat == 1 ? Wq : Wv);
  float v = W[c * 64 + h];
  if (mat == 1) v *= 0.18033688011112042f;  // 8^-1 * log2(e)
  Wt[idx] = f2bf(v);
}

// QKV projection. B (Wt) staged in LDS per BK=64 via async copy, XOR-swizzled.
// A (x) double-buffered in VGPRs: next k-step's loads issue right after the
// drain barrier, so their HBM latency hides under this step's compute instead
// of being exposed at the drain. 64 rows/block, 4 waves x 16 rows x 192 cols;
// 24 KB LDS -> 4 blocks/CU for overlap.
__global__ __launch_bounds__(256, 4) void qkv_kernel(
    const float* __restrict__ x, const ushort* __restrict__ Wt,
    ushort* __restrict__ Kb, ushort* __restrict__ Qb, ushort* __restrict__ Vt) {
  __shared__ __align__(16) ushort Bs[192 * 64];  // 24 KB
  int tid = threadIdx.x;
  int wave = tid >> 6, lane = tid & 63, quad = lane >> 4, l16 = lane & 15;
  int r0 = blockIdx.x * 64;
  const float* xr = x + (size_t)(r0 + wave * 16 + l16) * C_;

  f32x4 acc[12];
#pragma unroll
  for (int nt = 0; nt < 12; ++nt) acc[nt] = (f32x4){0.f, 0.f, 0.f, 0.f};

  // A prefetch (k0 = 0); drained by the first compute barrier
  float4 a0 = *(const float4*)(xr + quad * 8);
  float4 a1 = *(const float4*)(xr + quad * 8 + 4);
  float4 a2 = *(const float4*)(xr + 32 + quad * 8);
  float4 a3 = *(const float4*)(xr + 32 + quad * 8 + 4);

  for (int k0 = 0; k0 < C_; k0 += 64) {
    __syncthreads();  // all waves done reading previous B tile
    // stage B: 192 rows x 8 chunks (16B = 8 bf16); src chunk c = p ^ (n&7)
#pragma unroll
    for (int i = 0; i < 6; ++i) {
      int id = tid + 256 * i;
      int n = id >> 3, p = id & 7, c = p ^ (n & 7);
      async_copy16((char*)Bs + id * 16, Wt + (size_t)n * C_ + k0 + c * 8);
    }
    __syncthreads();  // B staged (vmcnt(0) drain also covers A loads)

    // prefetch next A-tile; latency overlaps the compute below
    float4 n0 = a0, n1 = a1, n2 = a2, n3 = a3;
    if (k0 + 64 < C_) {
      n0 = *(const float4*)(xr + k0 + 64 + quad * 8);
      n1 = *(const float4*)(xr + k0 + 64 + quad * 8 + 4);
      n2 = *(const float4*)(xr + k0 + 96 + quad * 8);
      n3 = *(const float4*)(xr + k0 + 96 + quad * 8 + 4);
    }

    bf16x8 af0 = pack8(a0, a1);
    bf16x8 af1 = pack8(a2, a3);
#pragma unroll
    for (int nt = 0; nt < 12; ++nt) {
      int n = nt * 16 + l16;  // n&7 == l16&7
      bf16x8 b0 = *(const bf16x8*)(Bs + n * 64 + ((quad ^ (l16 & 7)) << 3));
      bf16x8 b1 = *(const bf16x8*)(Bs + n * 64 + (((4 + quad) ^ (l16 & 7)) << 3));
      acc[nt] = __builtin_amdgcn_mfma_f32_16x16x32_bf16(af0, b0, acc[nt], 0, 0, 0);
      acc[nt] = __builtin_amdgcn_mfma_f32_16x16x32_bf16(af1, b1, acc[nt], 0, 0, 0);
    }
    a0 = n0; a1 = n1; a2 = n2; a3 = n3;
  }

  // epilogue. C layout: col(h) = l16, row = quad*4 + r
  int b = r0 >> 11;
  int rowbase = r0 + wave * 16 + quad * 4;
#pragma unroll
  for (int nt = 0; nt < 12; ++nt) {
    int mat = nt >> 2;
    int h = (nt & 3) * 16 + l16;
    if (mat == 2) {  // V: packed 4x bf16 store along t (transposed layout)
      ushort4 pv;
      pv.x = f2bf(acc[nt][0]); pv.y = f2bf(acc[nt][1]);
      pv.z = f2bf(acc[nt][2]); pv.w = f2bf(acc[nt][3]);
      *(ushort4*)(&Vt[(size_t)b * H_ * T_ + (size_t)h * T_ + (rowbase & (T_ - 1))]) = pv;
    } else {
      ushort* dst = (mat == 0) ? Kb : Qb;
#pragma unroll
      for (int r = 0; r < 4; ++r)
        dst[(size_t)(rowbase + r) * H_ + h] = f2bf(acc[nt][r]);
    }
  }
}

// Flash attention, load-balanced, KVBLK=128, SWAPPED QK^T (in-register P).
// mfma(K,Q) puts S^T in the C-file: each lane owns ONE q-row (q = q0+l16) with
// j-values at nt*16 + quad*4 + rr. That per-lane j-ownership is exactly the
// B-fragment layout of v_mfma_f32_16x16x16_bf16 (k = quad*4+i), so PV consumes
// P directly from 16 v_cvt_pk_bf16_f32 per chunk -- no LDS round-trip, no
// cross-lane exchange, no f2bf chain. Row-max/l/m are per-lane scalars
// (+2 shfl_xor across quads). Epilogue: coalesced float4 stores of O^T tiles.
// Chunks double-buffered, one barrier per chunk (stage(jc+1) drains at the
// NEXT barrier). Deferred-max rescale (threshold 8 log2 units, P <= 2^8).
// Segment pair (31-s, s): exactly 17 chunks per block. LDS 64 KB -> 2/CU.
__global__ __launch_bounds__(256, 2) void attn_kernel(
    const ushort* __restrict__ Qb, const ushort* __restrict__ Kb,
    const ushort* __restrict__ Vt, float* __restrict__ out) {
  __shared__ __align__(16) ushort Ks[2][128 * 64];   // 32 KB: K[j][h] x2
  __shared__ __align__(16) ushort Vs[2][64 * 128];   // 32 KB: V^T[h][j] x2

  int tid = threadIdx.x;
  int wave = tid >> 6, lane = tid & 63, quad = lane >> 4, l16 = lane & 15;
  int bid = blockIdx.x;
  int xcd = bid & 7, wi = bid >> 3;
  int batch = xcd * 4 + (wi & 3);  // 4 batches per XCD
  int spair = wi >> 2;             // 0..15
  const ushort* Qbase = Qb + (size_t)batch * T_ * H_;
  const ushort* Kbase = Kb + (size_t)batch * T_ * H_;
  const ushort* Vbase = Vt + (size_t)batch * H_ * T_;

  auto stage = [&](int jc, int buf) {
    int j0 = jc * 128;
    // K: 128 rows x 8 chunks; pre-swizzled source c = p ^ (n&7)
#pragma unroll
    for (int g = 0; g < 4; ++g) {
      int id = tid + 256 * g;
      int n = id >> 3, p = id & 7, c = p ^ (n & 7);
      async_copy16((char*)&Ks[buf][0] + id * 16,
                   Kbase + (size_t)(j0 + n) * H_ + c * 8);
    }
    // V^T: 64 rows x 16 chunks; pre-swizzled source c = p ^ (r&15)
#pragma unroll
    for (int g = 0; g < 4; ++g) {
      int id = tid + 256 * g;
      int r = id >> 4, p = id & 15, c = p ^ (r & 15);
      async_copy16((char*)&Vs[buf][0] + id * 16,
                   Vbase + (size_t)r * T_ + j0 + c * 8);
    }
  };

#pragma unroll 1
  for (int half = 0; half < 2; ++half) {
    int qseg = half ? spair : 31 - spair;  // heavy segment first
    int q0 = qseg * 64 + wave * 16;
    const ushort* qr = Qbase + (size_t)(q0 + l16) * H_;
    bf16x8 qf0 = *(const bf16x8*)(qr + quad * 8);
    bf16x8 qf1 = *(const bf16x8*)(qr + 32 + quad * 8);

    f32x4 o[4];
#pragma unroll
    for (int i = 0; i < 4; ++i) o[i] = (f32x4){0.f, 0.f, 0.f, 0.f};
    float m_i = -1e30f, l_i = 0.f;  // per-lane row q = q0 + l16

    int nch = (qseg >> 1) + 1;  // 128-j chunks; last may overshoot (masked)
    __syncthreads();            // previous half's reads of buf 0 complete
    stage(0, 0);
    int cur = 0;
#pragma unroll 1
    for (int jc = 0; jc < nch; ++jc, cur ^= 1) {
      int j0 = jc * 128;
      __syncthreads();  // stage(jc) drained; prev compute's buf reads done
      if (jc + 1 < nch) stage(jc + 1, cur ^ 1);  // overlaps with compute below
      const ushort* KsC = &Ks[cur][0];
      const ushort* VsC = &Vs[cur][0];

      // S^T = K Q^T : lane holds row q = q0+l16, j = j0 + nt*16 + quad*4 + rr
      f32x4 sv[8];
      __builtin_amdgcn_s_setprio(1);
#pragma unroll
      for (int nt = 0; nt < 8; ++nt) {
        int n = nt * 16 + l16;  // n&7 == l16&7
        bf16x8 kf0 = *(const bf16x8*)(KsC + n * 64 + ((quad ^ (l16 & 7)) << 3));
        bf16x8 kf1 = *(const bf16x8*)(KsC + n * 64 + (((4 + quad) ^ (l16 & 7)) << 3));
        f32x4 z = (f32x4){0.f, 0.f, 0.f, 0.f};
        z = __builtin_amdgcn_mfma_f32_16x16x32_bf16(kf0, qf0, z, 0, 0, 0);
        z = __builtin_amdgcn_mfma_f32_16x16x32_bf16(kf1, qf1, z, 0, 0, 0);
        sv[nt] = z;
      }
      __builtin_amdgcn_s_setprio(0);

      if (jc == nch - 1) {  // causal mask (provably only the last chunk)
        int qg = q0 + l16;
#pragma unroll
        for (int nt = 0; nt < 8; ++nt) {
          int jb = j0 + nt * 16 + quad * 4;
#pragma unroll
          for (int rr = 0; rr < 4; ++rr)
            if (jb + rr > qg) sv[nt][rr] = -1e30f;
        }
      }

      // row max: in-lane tree over 32 values + 2 cross-quad shfls
      float t8[8];
#pragma unroll
      for (int nt = 0; nt < 8; ++nt)
        t8[nt] = fmaxf(fmaxf(sv[nt][0], sv[nt][1]), fmaxf(sv[nt][2], sv[nt][3]));
      float pm = fmaxf(fmaxf(fmaxf(t8[0], t8[1]), fmaxf(t8[2], t8[3])),
                       fmaxf(fmaxf(t8[4], t8[5]), fmaxf(t8[6], t8[7])));
      pm = fmaxf(pm, __shfl_xor(pm, 16));
      pm = fmaxf(pm, __shfl_xor(pm, 32));

      // deferred-max: only rescale when the max actually grows (>8 log2 units)
      if (__any(pm > m_i + 8.f)) {
        float mn = fmaxf(m_i, pm);
        float alpha = exp2f(m_i - mn);
        m_i = mn; l_i *= alpha;
#pragma unroll
        for (int ht = 0; ht < 4; ++ht)
#pragma unroll
          for (int rr = 0; rr < 4; ++rr) o[ht][rr] *= alpha;
      }

      // P = exp2(S - m), packed straight into MFMA16 B-fragments
      unsigned pk[8][2];
      float rs = 0.f;
#pragma unroll
      for (int nt = 0; nt < 8; ++nt) {
        float p0 = exp2f(sv[nt][0] - m_i);
        float p1 = exp2f(sv[nt][1] - m_i);
        float p2 = exp2f(sv[nt][2] - m_i);
        float p3 = exp2f(sv[nt][3] - m_i);
        rs += (p0 + p1) + (p2 + p3);
        pk[nt][0] = cvt_pk_bf16(p0, p1);
        pk[nt][1] = cvt_pk_bf16(p2, p3);
      }
      l_i += rs;

      // O^T += V^T P^T : A = V^T rows (h), B = pk (k = quad*4+i == j-ownership)
      __builtin_amdgcn_s_setprio(1);
#pragma unroll
      for (int ht = 0; ht < 4; ++ht) {
        int rowb = (ht * 16 + l16) * 128;
#pragma unroll
        for (int nt = 0; nt < 8; ++nt) {
          int chk = (nt * 2 + (quad >> 1)) ^ l16;  // stored-chunk swizzle
          bf16x4 vf = *(const bf16x4*)(VsC + rowb + (chk << 3) + ((quad & 1) << 2));
          union { unsigned u[2]; bf16x4 v; } pb;
          pb.u[0] = pk[nt][0]; pb.u[1] = pk[nt][1];
          o[ht] = MFMA16(vf, pb.v, o[ht]);
        }
      }
      __builtin_amdgcn_s_setprio(0);
    }

    // finalize: l partials live across quads; O^T stores coalesce per 64B line
    float ls = l_i;
    ls += __shfl_xor(ls, 16);
    ls += __shfl_xor(ls, 32);
    float linv = __builtin_amdgcn_rcpf(ls);
    float* orow = out + ((size_t)batch * T_ + q0 + l16) * H_;
#pragma unroll
    for (int ht = 0; ht < 4; ++ht) {
      float4 st;
      st.x = o[ht][0] * linv; st.y = o[ht][1] * linv;
      st.z = o[ht][2] * linv; st.w = o[ht][3] * linv;
      *(float4*)(orow + ht * 16 + quad * 4) = st;
    }
  }
}

extern "C" void kernel_launch(void* const* d_in, const int* in_sizes, int n_in,
                              void* d_out, int out_size, void* d_ws, size_t ws_size,
                              hipStream_t stream) {
  const float* x  = (const float*)d_in[0];
  const float* Wk = (const float*)d_in[1];
  const float* Wq = (const float*)d_in[2];
  const float* Wv = (const float*)d_in[3];
  float* out = (float*)d_out;

  ushort* Wt = (ushort*)d_ws;                              // 384 KB
  ushort* Kb = (ushort*)((char*)d_ws + (1 << 19));         // 8 MB each
  ushort* Qb = Kb + (size_t)B_ * T_ * H_;
  ushort* Vt = Qb + (size_t)B_ * T_ * H_;                  // transposed [b][h][t]

  hipLaunchKernelGGL(wconv_kernel, dim3(768), dim3(256), 0, stream, Wk, Wq, Wv, Wt);
  hipLaunchKernelGGL(qkv_kernel, dim3(1024), dim3(256), 0, stream, x, Wt, Kb, Qb, Vt);
  hipLaunchKernelGGL(attn_kernel, dim3(512), dim3(256), 0, stream, Qb, Kb, Vt, out);
}